// Round 2
// 523.996 us; speedup vs baseline: 1.3389x; 1.3389x over previous
//
#include <hip/hip_runtime.h>

// Problem constants (match reference): B=4096, T=256, NC=16, NR=32, D=64
static constexpr int T_DIM = 256;
static constexpr int NC_DIM = 16;
static constexpr int D_DIM = 64;

// Block = 256 threads handles 16 rows (row = b*T + t).
// Waves 0-1 (tid 0..127): C-part, 8 threads/row, 2 channels/thread.
// Waves 2-3 (tid 128..255): R-part, 8 threads/row, 4 channels/thread.
// Divergence is wave-uniform -> free. Each exp/sincos computed exactly once.
__global__ __launch_bounds__(256) void linear_update_kernel(
    const float* __restrict__ y,
    const float* __restrict__ Km,
    float* __restrict__ out,
    long long nrows)
{
    const int tid = threadIdx.x;
    const long long row0 = (long long)blockIdx.x * 16;

    if (tid < 128) {
        // ---- C part: out[:, :, 0:32] ----
        const long long row = row0 + (tid >> 3);
        if (row >= nrows) return;
        const int c0 = (tid & 7) * 2;            // channels c0, c0+1 (0..15)
        const long long base = row * D_DIM;

        // y complex pairs for channels c0, c0+1: y[base + 2*c0 .. 2*c0+3]
        const float4 yv = *reinterpret_cast<const float4*>(y + base + 2 * c0);
        const float2 lg = *reinterpret_cast<const float2*>(Km + base + c0);
        const float2 th = *reinterpret_cast<const float2*>(Km + base + NC_DIM + c0);

        // logs, theta are ~0.01*N(0,1): tiny args -> HW exp/sin/cos are exact
        // to ~1e-6 absolute on O(1) outputs. Safe vs libm.
        const float s0 = __expf(lg.x);
        const float s1 = __expf(lg.y);
        float sn0, cs0, sn1, cs1;
        __sincosf(th.x, &sn0, &cs0);
        __sincosf(th.y, &sn1, &cs1);
        const float re0 = s0 * cs0, im0 = s0 * sn0;
        const float re1 = s1 * cs1, im1 = s1 * sn1;

        float2 o0, o1;
        o0.x = yv.x * re0 + yv.y * im0;          // out0[c0]
        o1.x = yv.y * re0 - yv.x * im0;          // out1[c0]
        o0.y = yv.z * re1 + yv.w * im1;          // out0[c0+1]
        o1.y = yv.w * re1 - yv.z * im1;          // out1[c0+1]

        *reinterpret_cast<float2*>(out + base + c0) = o0;
        *reinterpret_cast<float2*>(out + base + NC_DIM + c0) = o1;
    } else {
        // ---- R part: out[:, :, 32:64] ----
        const int i = tid - 128;
        const long long row = row0 + (i >> 3);
        if (row >= nrows) return;
        const int r0 = (i & 7) * 4;              // r channels r0..r0+3
        const int t = (int)(row & (T_DIM - 1));
        const long long base = row * D_DIM;
        const long long base0 = base - (long long)t * D_DIM;  // (b, t=0) row

        // t=0 row is reused by 256 consecutive rows -> L1/L2 resident.
        const float4 y0 = *reinterpret_cast<const float4*>(y + base0 + 2 * NC_DIM + r0);
        const float4 lr = *reinterpret_cast<const float4*>(Km + base0 + 2 * NC_DIM + r0);
        const float tf = (float)t;

        // Keep precise expf here: values reach ~2e5, fast-math ulp noise
        // would multiply into absolute error.
        float4 o;
        o.x = y0.x * expf(lr.x * tf);
        o.y = y0.y * expf(lr.y * tf);
        o.z = y0.z * expf(lr.z * tf);
        o.w = y0.w * expf(lr.w * tf);
        *reinterpret_cast<float4*>(out + base + 2 * NC_DIM + r0) = o;
    }
}

extern "C" void kernel_launch(void* const* d_in, const int* in_sizes, int n_in,
                              void* d_out, int out_size, void* d_ws, size_t ws_size,
                              hipStream_t stream) {
    const float* y  = (const float*)d_in[0];
    const float* Km = (const float*)d_in[1];
    float* out = (float*)d_out;

    const long long nrows = (long long)out_size / D_DIM;   // B*T = 1,048,576
    const int blocks = (int)((nrows + 15) / 16);           // 16 rows per block
    linear_update_kernel<<<blocks, 256, 0, stream>>>(y, Km, out, nrows);
}